// Round 5
// baseline (569.062 us; speedup 1.0000x reference)
//
#include <hip/hip_runtime.h>

// Problem constants (from reference):
//   q:(32,2048,1024) k:(2048,32,1024) v:(32,2048,1024) f32
//   Wq/Wk:(1024,512) bq/bk:(512) Ws:(512,1) bs:(1)
// reference: softmax over a size-1 axis == 1.0 exactly -> output is simply
//   out[b,e] = sum_n v[b,n,e]   (32,1024) f32
// Everything except v is dead code.

#define BSZ 32
#define NQ  2048
#define EMB 1024
#define E4  (EMB / 4)        // 256 float4 per row

constexpr int CHUNKS = 64;           // n-dimension split
constexpr int ROWS   = NQ / CHUNKS;  // 32 rows per block

// ---------------- Phase 1: per-(b,chunk) partial sums --------------------
// grid = BSZ*CHUNKS = 2048 blocks, block = 256 threads (one float4 col each)
// 2048 blocks / 256 CUs = 8 blocks/CU = 32 waves/CU -> full occupancy.
__global__ __launch_bounds__(256) void partial_sum_kernel(
    const float4* __restrict__ v, float4* __restrict__ part) {
    const int blk = blockIdx.x;          // 0..2047
    const int b   = blk / CHUNKS;
    const int c   = blk % CHUNKS;
    const int t   = threadIdx.x;         // 0..255 -> float4 column

    const float4* base = v + (size_t)b * NQ * E4 + (size_t)c * ROWS * E4 + t;
    float4 acc = make_float4(0.f, 0.f, 0.f, 0.f);
#pragma unroll
    for (int r = 0; r < ROWS; ++r) {
        float4 x = base[(size_t)r * E4];
        acc.x += x.x; acc.y += x.y; acc.z += x.z; acc.w += x.w;
    }
    part[(size_t)blk * E4 + t] = acc;
}

// ---------------- Phase 2: reduce CHUNKS partials -> out -----------------
// total outputs = BSZ*E4 = 8192 float4 -> 32 blocks x 256 threads
__global__ __launch_bounds__(256) void final_sum_kernel(
    const float4* __restrict__ part, float4* __restrict__ out) {
    const int idx = blockIdx.x * blockDim.x + threadIdx.x;  // 0..8191
    const int b   = idx / E4;
    const int e4  = idx % E4;

    const float4* p = part + (size_t)b * CHUNKS * E4 + e4;
    float4 acc = make_float4(0.f, 0.f, 0.f, 0.f);
#pragma unroll
    for (int c = 0; c < CHUNKS; ++c) {
        float4 x = p[(size_t)c * E4];
        acc.x += x.x; acc.y += x.y; acc.z += x.z; acc.w += x.w;
    }
    out[idx] = acc;
}

// ---------------- Fallback path (no workspace needed) --------------------
__global__ __launch_bounds__(256) void zero_kernel(float* __restrict__ out, int n) {
    int i = blockIdx.x * blockDim.x + threadIdx.x;
    if (i < n) out[i] = 0.f;
}

__global__ __launch_bounds__(256) void atomic_sum_kernel(
    const float4* __restrict__ v, float* __restrict__ out) {
    const int blk = blockIdx.x;
    const int b   = blk / CHUNKS;
    const int c   = blk % CHUNKS;
    const int t   = threadIdx.x;

    const float4* base = v + (size_t)b * NQ * E4 + (size_t)c * ROWS * E4 + t;
    float4 acc = make_float4(0.f, 0.f, 0.f, 0.f);
#pragma unroll
    for (int r = 0; r < ROWS; ++r) {
        float4 x = base[(size_t)r * E4];
        acc.x += x.x; acc.y += x.y; acc.z += x.z; acc.w += x.w;
    }
    float* o = out + (size_t)b * EMB + t * 4;
    atomicAdd(o + 0, acc.x);
    atomicAdd(o + 1, acc.y);
    atomicAdd(o + 2, acc.z);
    atomicAdd(o + 3, acc.w);
}

extern "C" void kernel_launch(void* const* d_in, const int* in_sizes, int n_in,
                              void* d_out, int out_size, void* d_ws, size_t ws_size,
                              hipStream_t stream) {
    // setup_inputs order: q, k, v, Wq, bq, Wk, bk, Ws, bs -> v is d_in[2]
    const float4* v   = (const float4*)d_in[2];
    float*        out = (float*)d_out;          // 32*1024 f32

    const size_t part_bytes = (size_t)BSZ * CHUNKS * EMB * sizeof(float); // 8 MiB

    if (ws_size >= part_bytes) {
        float4* part = (float4*)d_ws;
        partial_sum_kernel<<<BSZ * CHUNKS, 256, 0, stream>>>(v, part);
        final_sum_kernel<<<(BSZ * E4) / 256, 256, 0, stream>>>(part, (float4*)d_out);
    } else {
        zero_kernel<<<(BSZ * EMB + 255) / 256, 256, 0, stream>>>(out, BSZ * EMB);
        atomic_sum_kernel<<<BSZ * CHUNKS, 256, 0, stream>>>(v, out);
    }
}